// Round 10
// baseline (1901.312 us; speedup 1.0000x reference)
//
#include <hip/hip_runtime.h>
#include <stdint.h>
#include <algorithm>

#define BATCH 8
#define NPTS 16384
#define NPOINT 1024
#define KNN 32
#define SAMPLE_NUM 10
#define SELN 7
#define SUBSET 29
#define RADIUS 0.2f
#define CAP 2048
#define NTHREADS 1024
#define GRID_BLOCKS 256

typedef float f32x2 __attribute__((ext_vector_type(2)));
typedef float f32x4 __attribute__((ext_vector_type(4)));

// ---------------------------------------------------------------------------
// Host-side threefry2x32 replicating jax.random under the PARTITIONABLE
// implementation (jax_threefry_partitionable defaults True since JAX 0.4.36):
//   key(42) = (0,42)
//   fold_in(key,i)   = tf(key, (c0=0, c1=i))
//   split(folded)[1] = tf(folded, (c0=0, c1=1))
//   random_bits(subkey, 32, (32,)): lane j = tf(subkey, (0, j)), bits = o0^o1
//   permutation      = arange(32) stably sorted by bits ascending
// ---------------------------------------------------------------------------
struct PermTab { unsigned char p[SAMPLE_NUM][SUBSET]; };

static inline uint32_t rotl32h(uint32_t x, int d) { return (x << d) | (x >> (32 - d)); }

static void tf2x32(uint32_t k0, uint32_t k1, uint32_t c0, uint32_t c1,
                   uint32_t& o0, uint32_t& o1) {
    const uint32_t ks[3] = { k0, k1, k0 ^ k1 ^ 0x1BD11BDAu };
    uint32_t x0 = c0 + ks[0];
    uint32_t x1 = c1 + ks[1];
    static const int R[8] = {13, 15, 26, 6, 17, 29, 16, 24};
    for (int s = 0; s < 5; ++s) {
        const int* r = R + (s % 2) * 4;
        for (int j = 0; j < 4; ++j) {
            x0 += x1;
            x1 = rotl32h(x1, r[j]);
            x1 ^= x0;
        }
        x0 += ks[(s + 1) % 3];
        x1 += ks[(s + 2) % 3] + (uint32_t)(s + 1);
    }
    o0 = x0; o1 = x1;
}

static PermTab build_tab() {
    PermTab t;
    for (int i = 0; i < SAMPLE_NUM; ++i) {
        uint32_t f0, f1;
        tf2x32(0u, 42u, 0u, (uint32_t)i, f0, f1);
        uint32_t s0, s1;
        tf2x32(f0, f1, 0u, 1u, s0, s1);
        uint32_t bits[32];
        for (int j = 0; j < 32; ++j) {
            uint32_t o0, o1;
            tf2x32(s0, s1, 0u, (uint32_t)j, o0, o1);
            bits[j] = o0 ^ o1;
        }
        int perm[32];
        for (int j = 0; j < 32; ++j) perm[j] = j;
        std::stable_sort(perm, perm + 32, [&](int x, int y) {
            return bits[x] < bits[y];
        });
        for (int q = 0; q < SUBSET; ++q) t.p[i][q] = (unsigned char)perm[q];
    }
    return t;
}

// ---------------------------------------------------------------------------
// r17 = r16 (passing fused persistent kernel, -200 us) + DEFERRED PUBLISH.
// r16 post-mortem: fused dispatch 1745 us vs 1666 us fps floor. The ~80 us
// gap == per-iteration publish cost: a RELEASE store forces s_waitcnt
// vmcnt(0) BEFORE the atomic, making tid0 wait ~200 cyc for its 3 center
// stores to reach L2, and the barrier propagates that to all 16 waves,
// every iteration (1023 x 200 cyc ~= 85 us).
// Fix: release-store done=t in the MIDDLE of iteration t+1 (after the scan,
// before the wave reduce). By then center t's stores are ~1500 cyc old and
// retired -> the mandatory vmcnt drain counts nothing -> release is free,
// and it remains a true release (prior stores cannot sink below it).
// Consumers see center s one iteration (~1.6 us) later -- irrelevant, they
// are production-limited. Final done=NPOINT published once after the loop.
// All numerics/machinery identical to r16 (bit-identical winners/outputs).
// ---------------------------------------------------------------------------
#define REP8(M) M(0) M(1) M(2) M(3) M(4) M(5) M(6) M(7)

// f32 max across lanes, one DPP step (builtin: compiler inserts the DPP
// hazard nops -- r14 proved raw asm here is unsafe). old-preserve.
#define DPP_FMAX_STEP(v, ctrl) { \
        const int t_ = __builtin_amdgcn_update_dpp( \
            __float_as_int(v), __float_as_int(v), (ctrl), 0xf, 0xf, false); \
        (v) = fmaxf((v), __int_as_float(t_)); }

#define DPP_UMAX_STEP(v, ctrl) { \
        const unsigned t_ = (unsigned)__builtin_amdgcn_update_dpp( \
            (int)(v), (int)(v), (ctrl), 0xf, 0xf, false); \
        (v) = (t_ > (v)) ? t_ : (v); }

__global__ __launch_bounds__(NTHREADS) void fused_kernel(const float* __restrict__ xyz,
                                                         float* __restrict__ centers,
                                                         unsigned* __restrict__ syncb,
                                                         float* __restrict__ out,
                                                         PermTab tab) {
#pragma clang fp contract(off)
    const int bid = blockIdx.x;
    const int tid = threadIdx.x;

    // --- shared: fps role + knn role + feat staging (sum ~153 KB -> 1 block/CU)
    __shared__ f32x4 sPair[NPTS / 2];          // 128 KB (fps)
    __shared__ unsigned sk[2][2][16];          // fps reduce slots
    __shared__ unsigned hist[2048];            // knn radix histogram (8 KB)
    __shared__ unsigned ckey[CAP];             // knn candidates (8 KB)
    __shared__ int cidx[CAP];                  // knn candidates (8 KB)
    __shared__ int s_cnt;
    __shared__ int s_bstar;
    __shared__ int s_ticket;
    __shared__ float s_c[3];
    __shared__ float s_gl[KNN * 3];            // ranked neighbors for feat
    __shared__ float s_clx[SAMPLE_NUM], s_cly[SAMPLE_NUM], s_clz[SAMPLE_NUM];

    // =====================================================================
    // Role 1: FPS (blocks 0..7) -- r13 body + deferred publish
    // =====================================================================
    if (bid < BATCH) {
        const int b = bid;
        const int wv = tid >> 6;
        const int lane = tid & 63;
        const float* base = xyz + (size_t)b * NPTS * 3;
        unsigned* dput = syncb + 32 + b * 32;   // done[b], own cache line

#define P_DECL(j) f32x2 pz2##j, dd2##j;
        REP8(P_DECL)
#undef P_DECL

#define P_LOAD(j) { \
        const int q2 = (j) * 1024 + tid; \
        const f32x2 a = *(const f32x2*)&base[6 * q2]; \
        const f32x2 b2 = *(const f32x2*)&base[6 * q2 + 2]; \
        const f32x2 c = *(const f32x2*)&base[6 * q2 + 4]; \
        const f32x2 px2 = (f32x2){a.x, b2.y}; \
        const f32x2 py2 = (f32x2){a.y, c.x}; \
        pz2##j = (f32x2){b2.x, c.y}; \
        dd2##j = (f32x2){1e10f, 1e10f}; \
        sPair[q2] = (f32x4){px2.x, px2.y, py2.x, py2.y}; }
        REP8(P_LOAD)
#undef P_LOAD

        // Pin z pairs: asm defs cannot be rematerialized (r7 lesson).
#define P_PIN(j) asm volatile("" : "+v"(pz2##j));
        REP8(P_PIN)
#undef P_PIN

        float cx = base[0], cy = base[1], cz = base[2];
        if (tid == 0) {
            float* dst = centers + (size_t)b * NPOINT * 3;
            dst[0] = cx; dst[1] = cy; dst[2] = cz;
            __hip_atomic_store(dput, 1u, __ATOMIC_RELEASE,
                               __HIP_MEMORY_SCOPE_AGENT);
        }
        __syncthreads();   // sPair seeded

        const unsigned tb = (unsigned)tid * 2;

        for (int t = 1; t < NPOINT; ++t) {
            const int par = t & 1;
            const f32x2 ccx2 = (f32x2){cx, cx};
            const f32x2 ccy2 = (f32x2){cy, cy};
            const f32x2 ccz2 = (f32x2){cz, cz};
            float bv = -1.0f;
            unsigned bidx = 0;
            // ascending (j, lo->hi) = ascending global p; strict > keeps the
            // smallest index on ties (numpy argmax semantics, verified r3+).
#define P_SCAN(j) { \
            const f32x4 vv = sPair[(j) * 1024 + tid]; \
            const f32x2 dx = (f32x2){vv.x, vv.y} - ccx2; \
            const f32x2 dy = (f32x2){vv.z, vv.w} - ccy2; \
            const f32x2 dz = pz2##j - ccz2; \
            const f32x2 xx = dx * dx; \
            const f32x2 yy = dy * dy; \
            const f32x2 zz = dz * dz; \
            const f32x2 ss = xx + yy; \
            const f32x2 d2 = ss + zz; \
            const float nd0 = fminf(dd2##j.x, d2.x); \
            const float nd1 = fminf(dd2##j.y, d2.y); \
            dd2##j = (f32x2){nd0, nd1}; \
            if (nd0 > bv) { bv = nd0; bidx = (j) * 2; } \
            if (nd1 > bv) { bv = nd1; bidx = (j) * 2 + 1; } }
            REP8(P_SCAN)
#undef P_SCAN

            // DEFERRED publish of center t-1: its stores are ~1500 cyc old,
            // so the release's vmcnt(0) drain is free here (r16 paid ~200
            // cyc/iter doing this right after the stores).
            if (tid == 0) {
                __hip_atomic_store(dput, (unsigned)t, __ATOMIC_RELEASE,
                                   __HIP_MEMORY_SCOPE_AGENT);
            }

            float r = bv;
            DPP_FMAX_STEP(r, 0x111)
            DPP_FMAX_STEP(r, 0x112)
            DPP_FMAX_STEP(r, 0x114)
            DPP_FMAX_STEP(r, 0x118)
            DPP_FMAX_STEP(r, 0x142)
            DPP_FMAX_STEP(r, 0x143)
            const float wmax = __int_as_float(
                __builtin_amdgcn_readlane(__float_as_int(r), 63));

            const unsigned p = ((bidx >> 1) << 11) + tb + (bidx & 1);
            unsigned uk = (bv == wmax) ? ~p : 0u;   // max ~p = min p on ties
            DPP_UMAX_STEP(uk, 0x111)
            DPP_UMAX_STEP(uk, 0x112)
            DPP_UMAX_STEP(uk, 0x114)
            DPP_UMAX_STEP(uk, 0x118)
            DPP_UMAX_STEP(uk, 0x142)
            DPP_UMAX_STEP(uk, 0x143)

            if (lane == 63) {
                sk[par][0][wv] = __float_as_uint(r);
                sk[par][1][wv] = uk;
            }
            __syncthreads();

            const unsigned hi0 = sk[par][0][lane & 15];
            const unsigned lo0 = sk[par][1][lane & 15];
            unsigned h2 = hi0;
            DPP_UMAX_STEP(h2, 0x111)
            DPP_UMAX_STEP(h2, 0x112)
            DPP_UMAX_STEP(h2, 0x114)
            DPP_UMAX_STEP(h2, 0x118)
            const unsigned shi = (unsigned)__builtin_amdgcn_readlane((int)h2, 15);
            unsigned c2 = (hi0 == shi) ? lo0 : 0u;
            DPP_UMAX_STEP(c2, 0x111)
            DPP_UMAX_STEP(c2, 0x112)
            DPP_UMAX_STEP(c2, 0x114)
            DPP_UMAX_STEP(c2, 0x118)
            const unsigned slo = (unsigned)__builtin_amdgcn_readlane((int)c2, 15);
            const int ps = (int)(~slo) & (NPTS - 1);   // masked (r15 safety)

            const f32x4 w4 = sPair[ps >> 1];
            const int h = ps & 1;
            cx = h ? w4.y : w4.x;
            cy = h ? w4.w : w4.z;
            cz = base[(size_t)ps * 3 + 2];

            if (tid == 0) {
                float* dst = centers + ((size_t)b * NPOINT + t) * 3;
                dst[0] = cx; dst[1] = cy; dst[2] = cz;
            }
        }

        // final publish: all centers stored; one paid vmcnt drain, once.
        if (tid == 0) {
            __hip_atomic_store(dput, (unsigned)NPOINT, __ATOMIC_RELEASE,
                               __HIP_MEMORY_SCOPE_AGENT);
        }
    }

    // =====================================================================
    // Role 2: knn+feat consumers (ALL blocks; fps blocks join when done)
    // =====================================================================
    for (;;) {
        if (tid == 0) s_ticket = (int)atomicAdd(&syncb[0], 1u);
        __syncthreads();
        const int q = s_ticket;
        if (q >= BATCH * NPOINT) break;      // uniform per block
        const int s = q >> 3;                // s-major: early tickets need
        const int b = q & 7;                 // early centers
        const int bs = b * NPOINT + s;
        const float* bse = xyz + (size_t)b * NPTS * 3;

        if (tid == 0) {
            unsigned* db = syncb + 32 + b * 32;
            // relaxed poll (no per-poll cache invalidate), then one acquire
            // to order the subsequent center loads.
            while (__hip_atomic_load(db, __ATOMIC_RELAXED,
                                     __HIP_MEMORY_SCOPE_AGENT) <= (unsigned)s)
                __builtin_amdgcn_s_sleep(4);
            (void)__hip_atomic_load(db, __ATOMIC_ACQUIRE,
                                    __HIP_MEMORY_SCOPE_AGENT);
            float* cp = centers + (size_t)bs * 3;
            s_c[0] = __hip_atomic_load(cp + 0, __ATOMIC_RELAXED,
                                       __HIP_MEMORY_SCOPE_AGENT);
            s_c[1] = __hip_atomic_load(cp + 1, __ATOMIC_RELAXED,
                                       __HIP_MEMORY_SCOPE_AGENT);
            s_c[2] = __hip_atomic_load(cp + 2, __ATOMIC_RELAXED,
                                       __HIP_MEMORY_SCOPE_AGENT);
            s_cnt = 0;
        }
        for (int h = tid; h < 2048; h += NTHREADS) hist[h] = 0;
        __syncthreads();

        const float cx = s_c[0], cy = s_c[1], cz = s_c[2];
        const float sc = __fadd_rn(__fadd_rn(__fmul_rn(cx, cx), __fmul_rn(cy, cy)),
                                   __fmul_rn(cz, cz));

        for (int j = tid; j < NPTS; j += NTHREADS) {
            const float xx = bse[j * 3 + 0], xy = bse[j * 3 + 1], xz = bse[j * 3 + 2];
            const float sxj = __fadd_rn(__fadd_rn(__fmul_rn(xx, xx), __fmul_rn(xy, xy)),
                                        __fmul_rn(xz, xz));
            const float dot = __fadd_rn(__fadd_rn(__fmul_rn(cx, xx), __fmul_rn(cy, xy)),
                                        __fmul_rn(cz, xz));
            const float d2v = __fsub_rn(__fadd_rn(sc, sxj), __fmul_rn(2.0f, dot));
            unsigned u = __float_as_uint(d2v);
            unsigned key = u ^ ((u & 0x80000000u) ? 0xFFFFFFFFu : 0x80000000u);
            atomicAdd(&hist[key >> 21], 1u);
        }
        __syncthreads();

        if (tid < 64) {
            unsigned sum = 0;
#pragma unroll
            for (int q2 = 0; q2 < 32; ++q2) sum += hist[tid * 32 + q2];
            unsigned incl = sum;
            for (int d = 1; d < 64; d <<= 1) {
                unsigned o = __shfl_up(incl, d, 64);
                if (tid >= d) incl += o;
            }
            unsigned long long m = __ballot(incl >= 32u);
            int L = __ffsll(m) - 1;
            if (tid == L) {
                unsigned cum = incl - sum;
                int bb = L * 32 + 31;
                for (int q2 = 0; q2 < 32; ++q2) {
                    cum += hist[L * 32 + q2];
                    if (cum >= 32u) { bb = L * 32 + q2; break; }
                }
                s_bstar = bb;
            }
        }
        __syncthreads();

        const int bst = s_bstar;
        for (int j = tid; j < NPTS; j += NTHREADS) {
            const float xx = bse[j * 3 + 0], xy = bse[j * 3 + 1], xz = bse[j * 3 + 2];
            const float sxj = __fadd_rn(__fadd_rn(__fmul_rn(xx, xx), __fmul_rn(xy, xy)),
                                        __fmul_rn(xz, xz));
            const float dot = __fadd_rn(__fadd_rn(__fmul_rn(cx, xx), __fmul_rn(cy, xy)),
                                        __fmul_rn(cz, xz));
            const float d2v = __fsub_rn(__fadd_rn(sc, sxj), __fmul_rn(2.0f, dot));
            unsigned u = __float_as_uint(d2v);
            unsigned key = u ^ ((u & 0x80000000u) ? 0xFFFFFFFFu : 0x80000000u);
            if ((int)(key >> 21) <= bst) {
                int pos = atomicAdd(&s_cnt, 1);
                if (pos < CAP) { ckey[pos] = key; cidx[pos] = j; }
            }
        }
        __syncthreads();

        const int L2c = min(s_cnt, CAP);
        for (int c = tid; c < L2c; c += NTHREADS) {
            const unsigned k = ckey[c];
            const int id = cidx[c];
            int rank = 0;
            for (int m2 = 0; m2 < L2c; ++m2) {
                const unsigned km = ckey[m2];
                rank += (km < k || (km == k && cidx[m2] < id)) ? 1 : 0;
            }
            if (rank < KNN) {
                s_gl[rank * 3 + 0] = bse[id * 3 + 0];
                s_gl[rank * 3 + 1] = bse[id * 3 + 1];
                s_gl[rank * 3 + 2] = bse[id * 3 + 2];
            }
        }
        __syncthreads();

        // ---- feat phase B: 10 robust-centroid candidates in parallel
        if (tid < SAMPLE_NUM) {
            float sxm = 0.f, sym = 0.f, szm = 0.f;
            for (int j2 = 0; j2 < SUBSET; ++j2) {
                const int pp = tab.p[tid][j2];
                sxm = __fadd_rn(sxm, s_gl[pp * 3 + 0]);
                sym = __fadd_rn(sym, s_gl[pp * 3 + 1]);
                szm = __fadd_rn(szm, s_gl[pp * 3 + 2]);
            }
            s_clx[tid] = __fdiv_rn(sxm, 29.0f);
            s_cly[tid] = __fdiv_rn(sym, 29.0f);
            s_clz[tid] = __fdiv_rn(szm, 29.0f);
        }
        __syncthreads();

        // ---- feat phase C: serial tail on tid0 (numerics = feat_kernel)
        if (tid == 0) {
            float clx[SAMPLE_NUM], cly[SAMPLE_NUM], clz[SAMPLE_NUM];
#pragma unroll
            for (int i = 0; i < SAMPLE_NUM; ++i) {
                clx[i] = s_clx[i]; cly[i] = s_cly[i]; clz[i] = s_clz[i];
            }
            float sq[SAMPLE_NUM];
#pragma unroll
            for (int i = 0; i < SAMPLE_NUM; ++i)
                sq[i] = __fadd_rn(__fadd_rn(__fmul_rn(clx[i], clx[i]), __fmul_rn(cly[i], cly[i])),
                                  __fmul_rn(clz[i], clz[i]));
            float psv[SAMPLE_NUM];
#pragma unroll
            for (int i = 0; i < SAMPLE_NUM; ++i) {
                float pd[SAMPLE_NUM];
#pragma unroll
                for (int j2 = 0; j2 < SAMPLE_NUM; ++j2) {
                    float dot = __fadd_rn(__fadd_rn(__fmul_rn(clx[i], clx[j2]), __fmul_rn(cly[i], cly[j2])),
                                          __fmul_rn(clz[i], clz[j2]));
                    pd[j2] = __fsub_rn(__fadd_rn(sq[i], sq[j2]), __fmul_rn(2.0f, dot));
                }
                float res = __fadd_rn(__fadd_rn(__fadd_rn(pd[0], pd[1]), __fadd_rn(pd[2], pd[3])),
                                      __fadd_rn(__fadd_rn(pd[4], pd[5]), __fadd_rn(pd[6], pd[7])));
                res = __fadd_rn(res, pd[8]);
                res = __fadd_rn(res, pd[9]);
                psv[i] = res;
            }
            int rnk[SAMPLE_NUM];
#pragma unroll
            for (int j2 = 0; j2 < SAMPLE_NUM; ++j2) {
                int r = 0;
#pragma unroll
                for (int m = 0; m < SAMPLE_NUM; ++m)
                    r += (psv[m] < psv[j2] || (psv[m] == psv[j2] && m < j2)) ? 1 : 0;
                rnk[j2] = r;
            }
            float csx = 0.f, csy = 0.f, csz = 0.f;
            for (int r = 0; r < SELN; ++r) {
#pragma unroll
                for (int j2 = 0; j2 < SAMPLE_NUM; ++j2) {
                    if (rnk[j2] == r) {
                        csx = __fadd_rn(csx, clx[j2]);
                        csy = __fadd_rn(csy, cly[j2]);
                        csz = __fadd_rn(csz, clz[j2]);
                    }
                }
            }
            const float ccx = __fdiv_rn(csx, 7.0f);
            const float ccy = __fdiv_rn(csy, 7.0f);
            const float ccz = __fdiv_rn(csz, 7.0f);

            const float nx = cx, ny = cy, nz = cz;
            const float ref_norm = __fsqrt_rn(__fadd_rn(
                __fadd_rn(__fmul_rn(nx, nx), __fmul_rn(ny, ny)), __fmul_rn(nz, nz)));
            const float den = __fadd_rn(ref_norm, 1e-4f);
            const float ux = __fdiv_rn(nx, den), uy = __fdiv_rn(ny, den), uz = __fdiv_rn(nz, den);
            const float ix = __fadd_rn(__fmul_rn(RADIUS, ux), nx);
            const float iy = __fadd_rn(__fmul_rn(RADIUS, uy), ny);
            const float iz = __fadd_rn(__fmul_rn(RADIUS, uz), nz);

            const float crvx = __fsub_rn(nx, ccx), crvy = __fsub_rn(ny, ccy), crvz = __fsub_rn(nz, ccz);
            const float crd = __fsqrt_rn(__fadd_rn(
                __fadd_rn(__fmul_rn(crvx, crvx), __fmul_rn(crvy, crvy)), __fmul_rn(crvz, crvz)));
            const float civx = __fsub_rn(ix, ccx), civy = __fsub_rn(iy, ccy), civz = __fsub_rn(iz, ccz);
            const float cid = __fsqrt_rn(__fadd_rn(
                __fadd_rn(__fmul_rn(civx, civx), __fmul_rn(civy, civy)), __fmul_rn(civz, civz)));
            const float dot = __fadd_rn(__fadd_rn(__fmul_rn(crvx, civx), __fmul_rn(crvy, civy)),
                                        __fmul_rn(crvz, civz));
            const float ang_rci = __fdiv_rn(dot, __fadd_rn(__fmul_rn(crd, cid), 1e-6f));

            const float irvx = __fsub_rn(nx, ix), irvy = __fsub_rn(ny, iy), irvz = __fsub_rn(nz, iz);
            const float icvx = __fsub_rn(ccx, ix), icvy = __fsub_rn(ccy, iy), icvz = __fsub_rn(ccz, iz);
            const float dot2 = __fadd_rn(__fadd_rn(__fmul_rn(irvx, icvx), __fmul_rn(irvy, icvy)),
                                         __fmul_rn(irvz, icvz));
            const float ang_ric = __fdiv_rn(dot2, __fadd_rn(__fmul_rn(RADIUS, cid), 1e-6f));

            float* o = out + (size_t)bs * 5;
            o[0] = ref_norm;
            o[1] = crd;
            o[2] = cid;
            o[3] = ang_rci;
            o[4] = ang_ric;
        }
        __syncthreads();   // LDS reuse barrier before next ticket
    }
}

// ---------------------------------------------------------------------------
extern "C" void kernel_launch(void* const* d_in, const int* in_sizes, int n_in,
                              void* d_out, int out_size, void* d_ws, size_t ws_size,
                              hipStream_t stream) {
    const float* xyz = (const float*)d_in[0];
    float* out = (float*)d_out;

    // ws: [0..2048) sync region (ticket @0, done[b] @ (32+b*32)*4),
    //     then centers (B*NPOINT*3 floats)
    unsigned* syncb = (unsigned*)d_ws;
    float* centers = (float*)((char*)d_ws + 2048);

    static PermTab tab = build_tab();  // deterministic, host-only

    (void)hipMemsetAsync(syncb, 0, 2048, stream);
    fused_kernel<<<GRID_BLOCKS, NTHREADS, 0, stream>>>(xyz, centers, syncb, out, tab);
}

// Round 11
// 1766.180 us; speedup vs baseline: 1.0765x; 1.0765x over previous
//
#include <hip/hip_runtime.h>
#include <stdint.h>
#include <algorithm>

#define BATCH 8
#define NPTS 16384
#define NPOINT 1024
#define KNN 32
#define SAMPLE_NUM 10
#define SELN 7
#define SUBSET 29
#define RADIUS 0.2f
#define CAP 2048
#define NTHREADS 1024
#define GRID_BLOCKS 256

typedef float f32x2 __attribute__((ext_vector_type(2)));
typedef float f32x4 __attribute__((ext_vector_type(4)));

// ---------------------------------------------------------------------------
// Host-side threefry2x32 replicating jax.random under the PARTITIONABLE
// implementation (jax_threefry_partitionable defaults True since JAX 0.4.36):
//   key(42) = (0,42)
//   fold_in(key,i)   = tf(key, (c0=0, c1=i))
//   split(folded)[1] = tf(folded, (c0=0, c1=1))
//   random_bits(subkey, 32, (32,)): lane j = tf(subkey, (0, j)), bits = o0^o1
//   permutation      = arange(32) stably sorted by bits ascending
// ---------------------------------------------------------------------------
struct PermTab { unsigned char p[SAMPLE_NUM][SUBSET]; };

static inline uint32_t rotl32h(uint32_t x, int d) { return (x << d) | (x >> (32 - d)); }

static void tf2x32(uint32_t k0, uint32_t k1, uint32_t c0, uint32_t c1,
                   uint32_t& o0, uint32_t& o1) {
    const uint32_t ks[3] = { k0, k1, k0 ^ k1 ^ 0x1BD11BDAu };
    uint32_t x0 = c0 + ks[0];
    uint32_t x1 = c1 + ks[1];
    static const int R[8] = {13, 15, 26, 6, 17, 29, 16, 24};
    for (int s = 0; s < 5; ++s) {
        const int* r = R + (s % 2) * 4;
        for (int j = 0; j < 4; ++j) {
            x0 += x1;
            x1 = rotl32h(x1, r[j]);
            x1 ^= x0;
        }
        x0 += ks[(s + 1) % 3];
        x1 += ks[(s + 2) % 3] + (uint32_t)(s + 1);
    }
    o0 = x0; o1 = x1;
}

static PermTab build_tab() {
    PermTab t;
    for (int i = 0; i < SAMPLE_NUM; ++i) {
        uint32_t f0, f1;
        tf2x32(0u, 42u, 0u, (uint32_t)i, f0, f1);
        uint32_t s0, s1;
        tf2x32(f0, f1, 0u, 1u, s0, s1);
        uint32_t bits[32];
        for (int j = 0; j < 32; ++j) {
            uint32_t o0, o1;
            tf2x32(s0, s1, 0u, (uint32_t)j, o0, o1);
            bits[j] = o0 ^ o1;
        }
        int perm[32];
        for (int j = 0; j < 32; ++j) perm[j] = j;
        std::stable_sort(perm, perm + 32, [&](int x, int y) {
            return bits[x] < bits[y];
        });
        for (int q = 0; q < SUBSET; ++q) t.p[i][q] = (unsigned char)perm[q];
    }
    return t;
}

// ---------------------------------------------------------------------------
// r18 = r16 (best passing config, 1766 us) with THROTTLED publish.
// r17 post-mortem: moving the release into mid-iteration made things WORSE
// (1745 -> 1876 dispatch) -- the release's wait/writeback blocked entry to
// the DPP reduce; the r16 end-of-iteration site was already the good one.
// So the discriminating experiment for the remaining ~80 us gap over the
// 1666 us fps floor: keep the r16 publish SITE exactly, but publish only
// every 8th iteration ((t+1)%8==0 -> done jumps 8,16,...,1024). If the gap
// was publish cost (~200 cyc x 1023), this recovers ~7/8 of it; if it is
// consumer interference / drain tail, this is neutral -- and the composite
// is at its roofline (fps structurally pinned across 9 falsified variants,
// consumer overlap already captured).
// Consumers lag <= 8 centers (~13 us) -- irrelevant: consumption capacity
// (~16 tickets/us on 248 blocks) is ~3x production rate (4.9 centers/us);
// the last 64 tickets start together on 248 idle blocks (~+1 ticket-round
// ~15 us drain, paid once). Poll `done[b] > s` works unchanged on stepped
// values. All numerics/machinery identical to r16 (bit-identical outputs).
// ---------------------------------------------------------------------------
#define REP8(M) M(0) M(1) M(2) M(3) M(4) M(5) M(6) M(7)

// f32 max across lanes, one DPP step (builtin: compiler inserts the DPP
// hazard nops -- r14 proved raw asm here is unsafe). old-preserve.
#define DPP_FMAX_STEP(v, ctrl) { \
        const int t_ = __builtin_amdgcn_update_dpp( \
            __float_as_int(v), __float_as_int(v), (ctrl), 0xf, 0xf, false); \
        (v) = fmaxf((v), __int_as_float(t_)); }

#define DPP_UMAX_STEP(v, ctrl) { \
        const unsigned t_ = (unsigned)__builtin_amdgcn_update_dpp( \
            (int)(v), (int)(v), (ctrl), 0xf, 0xf, false); \
        (v) = (t_ > (v)) ? t_ : (v); }

__global__ __launch_bounds__(NTHREADS) void fused_kernel(const float* __restrict__ xyz,
                                                         float* __restrict__ centers,
                                                         unsigned* __restrict__ syncb,
                                                         float* __restrict__ out,
                                                         PermTab tab) {
#pragma clang fp contract(off)
    const int bid = blockIdx.x;
    const int tid = threadIdx.x;

    // --- shared: fps role + knn role + feat staging (sum ~153 KB -> 1 block/CU)
    __shared__ f32x4 sPair[NPTS / 2];          // 128 KB (fps)
    __shared__ unsigned sk[2][2][16];          // fps reduce slots
    __shared__ unsigned hist[2048];            // knn radix histogram (8 KB)
    __shared__ unsigned ckey[CAP];             // knn candidates (8 KB)
    __shared__ int cidx[CAP];                  // knn candidates (8 KB)
    __shared__ int s_cnt;
    __shared__ int s_bstar;
    __shared__ int s_ticket;
    __shared__ float s_c[3];
    __shared__ float s_gl[KNN * 3];            // ranked neighbors for feat
    __shared__ float s_clx[SAMPLE_NUM], s_cly[SAMPLE_NUM], s_clz[SAMPLE_NUM];

    // =====================================================================
    // Role 1: FPS (blocks 0..7) -- r13 body + throttled end-of-iter publish
    // =====================================================================
    if (bid < BATCH) {
        const int b = bid;
        const int wv = tid >> 6;
        const int lane = tid & 63;
        const float* base = xyz + (size_t)b * NPTS * 3;
        unsigned* dput = syncb + 32 + b * 32;   // done[b], own cache line

#define P_DECL(j) f32x2 pz2##j, dd2##j;
        REP8(P_DECL)
#undef P_DECL

#define P_LOAD(j) { \
        const int q2 = (j) * 1024 + tid; \
        const f32x2 a = *(const f32x2*)&base[6 * q2]; \
        const f32x2 b2 = *(const f32x2*)&base[6 * q2 + 2]; \
        const f32x2 c = *(const f32x2*)&base[6 * q2 + 4]; \
        const f32x2 px2 = (f32x2){a.x, b2.y}; \
        const f32x2 py2 = (f32x2){a.y, c.x}; \
        pz2##j = (f32x2){b2.x, c.y}; \
        dd2##j = (f32x2){1e10f, 1e10f}; \
        sPair[q2] = (f32x4){px2.x, px2.y, py2.x, py2.y}; }
        REP8(P_LOAD)
#undef P_LOAD

        // Pin z pairs: asm defs cannot be rematerialized (r7 lesson).
#define P_PIN(j) asm volatile("" : "+v"(pz2##j));
        REP8(P_PIN)
#undef P_PIN

        float cx = base[0], cy = base[1], cz = base[2];
        if (tid == 0) {
            float* dst = centers + (size_t)b * NPOINT * 3;
            dst[0] = cx; dst[1] = cy; dst[2] = cz;
            __hip_atomic_store(dput, 1u, __ATOMIC_RELEASE,
                               __HIP_MEMORY_SCOPE_AGENT);
        }
        __syncthreads();   // sPair seeded

        const unsigned tb = (unsigned)tid * 2;

        for (int t = 1; t < NPOINT; ++t) {
            const int par = t & 1;
            const f32x2 ccx2 = (f32x2){cx, cx};
            const f32x2 ccy2 = (f32x2){cy, cy};
            const f32x2 ccz2 = (f32x2){cz, cz};
            float bv = -1.0f;
            unsigned bidx = 0;
            // ascending (j, lo->hi) = ascending global p; strict > keeps the
            // smallest index on ties (numpy argmax semantics, verified r3+).
#define P_SCAN(j) { \
            const f32x4 vv = sPair[(j) * 1024 + tid]; \
            const f32x2 dx = (f32x2){vv.x, vv.y} - ccx2; \
            const f32x2 dy = (f32x2){vv.z, vv.w} - ccy2; \
            const f32x2 dz = pz2##j - ccz2; \
            const f32x2 xx = dx * dx; \
            const f32x2 yy = dy * dy; \
            const f32x2 zz = dz * dz; \
            const f32x2 ss = xx + yy; \
            const f32x2 d2 = ss + zz; \
            const float nd0 = fminf(dd2##j.x, d2.x); \
            const float nd1 = fminf(dd2##j.y, d2.y); \
            dd2##j = (f32x2){nd0, nd1}; \
            if (nd0 > bv) { bv = nd0; bidx = (j) * 2; } \
            if (nd1 > bv) { bv = nd1; bidx = (j) * 2 + 1; } }
            REP8(P_SCAN)
#undef P_SCAN

            float r = bv;
            DPP_FMAX_STEP(r, 0x111)
            DPP_FMAX_STEP(r, 0x112)
            DPP_FMAX_STEP(r, 0x114)
            DPP_FMAX_STEP(r, 0x118)
            DPP_FMAX_STEP(r, 0x142)
            DPP_FMAX_STEP(r, 0x143)
            const float wmax = __int_as_float(
                __builtin_amdgcn_readlane(__float_as_int(r), 63));

            const unsigned p = ((bidx >> 1) << 11) + tb + (bidx & 1);
            unsigned uk = (bv == wmax) ? ~p : 0u;   // max ~p = min p on ties
            DPP_UMAX_STEP(uk, 0x111)
            DPP_UMAX_STEP(uk, 0x112)
            DPP_UMAX_STEP(uk, 0x114)
            DPP_UMAX_STEP(uk, 0x118)
            DPP_UMAX_STEP(uk, 0x142)
            DPP_UMAX_STEP(uk, 0x143)

            if (lane == 63) {
                sk[par][0][wv] = __float_as_uint(r);
                sk[par][1][wv] = uk;
            }
            __syncthreads();

            const unsigned hi0 = sk[par][0][lane & 15];
            const unsigned lo0 = sk[par][1][lane & 15];
            unsigned h2 = hi0;
            DPP_UMAX_STEP(h2, 0x111)
            DPP_UMAX_STEP(h2, 0x112)
            DPP_UMAX_STEP(h2, 0x114)
            DPP_UMAX_STEP(h2, 0x118)
            const unsigned shi = (unsigned)__builtin_amdgcn_readlane((int)h2, 15);
            unsigned c2 = (hi0 == shi) ? lo0 : 0u;
            DPP_UMAX_STEP(c2, 0x111)
            DPP_UMAX_STEP(c2, 0x112)
            DPP_UMAX_STEP(c2, 0x114)
            DPP_UMAX_STEP(c2, 0x118)
            const unsigned slo = (unsigned)__builtin_amdgcn_readlane((int)c2, 15);
            const int ps = (int)(~slo) & (NPTS - 1);   // masked (r15 safety)

            const f32x4 w4 = sPair[ps >> 1];
            const int h = ps & 1;
            cx = h ? w4.y : w4.x;
            cy = h ? w4.w : w4.z;
            cz = base[(size_t)ps * 3 + 2];

            if (tid == 0) {
                float* dst = centers + ((size_t)b * NPOINT + t) * 3;
                dst[0] = cx; dst[1] = cy; dst[2] = cz;
                // throttled publish at the proven r16 site: 1/8 frequency
                if (((t + 1) & 7) == 0) {
                    __hip_atomic_store(dput, (unsigned)(t + 1), __ATOMIC_RELEASE,
                                       __HIP_MEMORY_SCOPE_AGENT);
                }
            }
        }

        // belt-and-braces final publish (idempotent; t=1023 already sent 1024)
        if (tid == 0) {
            __hip_atomic_store(dput, (unsigned)NPOINT, __ATOMIC_RELEASE,
                               __HIP_MEMORY_SCOPE_AGENT);
        }
    }

    // =====================================================================
    // Role 2: knn+feat consumers (ALL blocks; fps blocks join when done)
    // =====================================================================
    for (;;) {
        if (tid == 0) s_ticket = (int)atomicAdd(&syncb[0], 1u);
        __syncthreads();
        const int q = s_ticket;
        if (q >= BATCH * NPOINT) break;      // uniform per block
        const int s = q >> 3;                // s-major: early tickets need
        const int b = q & 7;                 // early centers
        const int bs = b * NPOINT + s;
        const float* bse = xyz + (size_t)b * NPTS * 3;

        if (tid == 0) {
            unsigned* db = syncb + 32 + b * 32;
            // relaxed poll (no per-poll cache invalidate), then one acquire
            // to order the subsequent center loads.
            while (__hip_atomic_load(db, __ATOMIC_RELAXED,
                                     __HIP_MEMORY_SCOPE_AGENT) <= (unsigned)s)
                __builtin_amdgcn_s_sleep(4);
            (void)__hip_atomic_load(db, __ATOMIC_ACQUIRE,
                                    __HIP_MEMORY_SCOPE_AGENT);
            float* cp = centers + (size_t)bs * 3;
            s_c[0] = __hip_atomic_load(cp + 0, __ATOMIC_RELAXED,
                                       __HIP_MEMORY_SCOPE_AGENT);
            s_c[1] = __hip_atomic_load(cp + 1, __ATOMIC_RELAXED,
                                       __HIP_MEMORY_SCOPE_AGENT);
            s_c[2] = __hip_atomic_load(cp + 2, __ATOMIC_RELAXED,
                                       __HIP_MEMORY_SCOPE_AGENT);
            s_cnt = 0;
        }
        for (int h = tid; h < 2048; h += NTHREADS) hist[h] = 0;
        __syncthreads();

        const float cx = s_c[0], cy = s_c[1], cz = s_c[2];
        const float sc = __fadd_rn(__fadd_rn(__fmul_rn(cx, cx), __fmul_rn(cy, cy)),
                                   __fmul_rn(cz, cz));

        for (int j = tid; j < NPTS; j += NTHREADS) {
            const float xx = bse[j * 3 + 0], xy = bse[j * 3 + 1], xz = bse[j * 3 + 2];
            const float sxj = __fadd_rn(__fadd_rn(__fmul_rn(xx, xx), __fmul_rn(xy, xy)),
                                        __fmul_rn(xz, xz));
            const float dot = __fadd_rn(__fadd_rn(__fmul_rn(cx, xx), __fmul_rn(cy, xy)),
                                        __fmul_rn(cz, xz));
            const float d2v = __fsub_rn(__fadd_rn(sc, sxj), __fmul_rn(2.0f, dot));
            unsigned u = __float_as_uint(d2v);
            unsigned key = u ^ ((u & 0x80000000u) ? 0xFFFFFFFFu : 0x80000000u);
            atomicAdd(&hist[key >> 21], 1u);
        }
        __syncthreads();

        if (tid < 64) {
            unsigned sum = 0;
#pragma unroll
            for (int q2 = 0; q2 < 32; ++q2) sum += hist[tid * 32 + q2];
            unsigned incl = sum;
            for (int d = 1; d < 64; d <<= 1) {
                unsigned o = __shfl_up(incl, d, 64);
                if (tid >= d) incl += o;
            }
            unsigned long long m = __ballot(incl >= 32u);
            int L = __ffsll(m) - 1;
            if (tid == L) {
                unsigned cum = incl - sum;
                int bb = L * 32 + 31;
                for (int q2 = 0; q2 < 32; ++q2) {
                    cum += hist[L * 32 + q2];
                    if (cum >= 32u) { bb = L * 32 + q2; break; }
                }
                s_bstar = bb;
            }
        }
        __syncthreads();

        const int bst = s_bstar;
        for (int j = tid; j < NPTS; j += NTHREADS) {
            const float xx = bse[j * 3 + 0], xy = bse[j * 3 + 1], xz = bse[j * 3 + 2];
            const float sxj = __fadd_rn(__fadd_rn(__fmul_rn(xx, xx), __fmul_rn(xy, xy)),
                                        __fmul_rn(xz, xz));
            const float dot = __fadd_rn(__fadd_rn(__fmul_rn(cx, xx), __fmul_rn(cy, xy)),
                                        __fmul_rn(cz, xz));
            const float d2v = __fsub_rn(__fadd_rn(sc, sxj), __fmul_rn(2.0f, dot));
            unsigned u = __float_as_uint(d2v);
            unsigned key = u ^ ((u & 0x80000000u) ? 0xFFFFFFFFu : 0x80000000u);
            if ((int)(key >> 21) <= bst) {
                int pos = atomicAdd(&s_cnt, 1);
                if (pos < CAP) { ckey[pos] = key; cidx[pos] = j; }
            }
        }
        __syncthreads();

        const int L2c = min(s_cnt, CAP);
        for (int c = tid; c < L2c; c += NTHREADS) {
            const unsigned k = ckey[c];
            const int id = cidx[c];
            int rank = 0;
            for (int m2 = 0; m2 < L2c; ++m2) {
                const unsigned km = ckey[m2];
                rank += (km < k || (km == k && cidx[m2] < id)) ? 1 : 0;
            }
            if (rank < KNN) {
                s_gl[rank * 3 + 0] = bse[id * 3 + 0];
                s_gl[rank * 3 + 1] = bse[id * 3 + 1];
                s_gl[rank * 3 + 2] = bse[id * 3 + 2];
            }
        }
        __syncthreads();

        // ---- feat phase B: 10 robust-centroid candidates in parallel
        if (tid < SAMPLE_NUM) {
            float sxm = 0.f, sym = 0.f, szm = 0.f;
            for (int j2 = 0; j2 < SUBSET; ++j2) {
                const int pp = tab.p[tid][j2];
                sxm = __fadd_rn(sxm, s_gl[pp * 3 + 0]);
                sym = __fadd_rn(sym, s_gl[pp * 3 + 1]);
                szm = __fadd_rn(szm, s_gl[pp * 3 + 2]);
            }
            s_clx[tid] = __fdiv_rn(sxm, 29.0f);
            s_cly[tid] = __fdiv_rn(sym, 29.0f);
            s_clz[tid] = __fdiv_rn(szm, 29.0f);
        }
        __syncthreads();

        // ---- feat phase C: serial tail on tid0 (numerics = feat_kernel)
        if (tid == 0) {
            float clx[SAMPLE_NUM], cly[SAMPLE_NUM], clz[SAMPLE_NUM];
#pragma unroll
            for (int i = 0; i < SAMPLE_NUM; ++i) {
                clx[i] = s_clx[i]; cly[i] = s_cly[i]; clz[i] = s_clz[i];
            }
            float sq[SAMPLE_NUM];
#pragma unroll
            for (int i = 0; i < SAMPLE_NUM; ++i)
                sq[i] = __fadd_rn(__fadd_rn(__fmul_rn(clx[i], clx[i]), __fmul_rn(cly[i], cly[i])),
                                  __fmul_rn(clz[i], clz[i]));
            float psv[SAMPLE_NUM];
#pragma unroll
            for (int i = 0; i < SAMPLE_NUM; ++i) {
                float pd[SAMPLE_NUM];
#pragma unroll
                for (int j2 = 0; j2 < SAMPLE_NUM; ++j2) {
                    float dot = __fadd_rn(__fadd_rn(__fmul_rn(clx[i], clx[j2]), __fmul_rn(cly[i], cly[j2])),
                                          __fmul_rn(clz[i], clz[j2]));
                    pd[j2] = __fsub_rn(__fadd_rn(sq[i], sq[j2]), __fmul_rn(2.0f, dot));
                }
                float res = __fadd_rn(__fadd_rn(__fadd_rn(pd[0], pd[1]), __fadd_rn(pd[2], pd[3])),
                                      __fadd_rn(__fadd_rn(pd[4], pd[5]), __fadd_rn(pd[6], pd[7])));
                res = __fadd_rn(res, pd[8]);
                res = __fadd_rn(res, pd[9]);
                psv[i] = res;
            }
            int rnk[SAMPLE_NUM];
#pragma unroll
            for (int j2 = 0; j2 < SAMPLE_NUM; ++j2) {
                int r = 0;
#pragma unroll
                for (int m = 0; m < SAMPLE_NUM; ++m)
                    r += (psv[m] < psv[j2] || (psv[m] == psv[j2] && m < j2)) ? 1 : 0;
                rnk[j2] = r;
            }
            float csx = 0.f, csy = 0.f, csz = 0.f;
            for (int r = 0; r < SELN; ++r) {
#pragma unroll
                for (int j2 = 0; j2 < SAMPLE_NUM; ++j2) {
                    if (rnk[j2] == r) {
                        csx = __fadd_rn(csx, clx[j2]);
                        csy = __fadd_rn(csy, cly[j2]);
                        csz = __fadd_rn(csz, clz[j2]);
                    }
                }
            }
            const float ccx = __fdiv_rn(csx, 7.0f);
            const float ccy = __fdiv_rn(csy, 7.0f);
            const float ccz = __fdiv_rn(csz, 7.0f);

            const float nx = cx, ny = cy, nz = cz;
            const float ref_norm = __fsqrt_rn(__fadd_rn(
                __fadd_rn(__fmul_rn(nx, nx), __fmul_rn(ny, ny)), __fmul_rn(nz, nz)));
            const float den = __fadd_rn(ref_norm, 1e-4f);
            const float ux = __fdiv_rn(nx, den), uy = __fdiv_rn(ny, den), uz = __fdiv_rn(nz, den);
            const float ix = __fadd_rn(__fmul_rn(RADIUS, ux), nx);
            const float iy = __fadd_rn(__fmul_rn(RADIUS, uy), ny);
            const float iz = __fadd_rn(__fmul_rn(RADIUS, uz), nz);

            const float crvx = __fsub_rn(nx, ccx), crvy = __fsub_rn(ny, ccy), crvz = __fsub_rn(nz, ccz);
            const float crd = __fsqrt_rn(__fadd_rn(
                __fadd_rn(__fmul_rn(crvx, crvx), __fmul_rn(crvy, crvy)), __fmul_rn(crvz, crvz)));
            const float civx = __fsub_rn(ix, ccx), civy = __fsub_rn(iy, ccy), civz = __fsub_rn(iz, ccz);
            const float cid = __fsqrt_rn(__fadd_rn(
                __fadd_rn(__fmul_rn(civx, civx), __fmul_rn(civy, civy)), __fmul_rn(civz, civz)));
            const float dot = __fadd_rn(__fadd_rn(__fmul_rn(crvx, civx), __fmul_rn(crvy, civy)),
                                        __fmul_rn(crvz, civz));
            const float ang_rci = __fdiv_rn(dot, __fadd_rn(__fmul_rn(crd, cid), 1e-6f));

            const float irvx = __fsub_rn(nx, ix), irvy = __fsub_rn(ny, iy), irvz = __fsub_rn(nz, iz);
            const float icvx = __fsub_rn(ccx, ix), icvy = __fsub_rn(ccy, iy), icvz = __fsub_rn(ccz, iz);
            const float dot2 = __fadd_rn(__fadd_rn(__fmul_rn(irvx, icvx), __fmul_rn(irvy, icvy)),
                                         __fmul_rn(irvz, icvz));
            const float ang_ric = __fdiv_rn(dot2, __fadd_rn(__fmul_rn(RADIUS, cid), 1e-6f));

            float* o = out + (size_t)bs * 5;
            o[0] = ref_norm;
            o[1] = crd;
            o[2] = cid;
            o[3] = ang_rci;
            o[4] = ang_ric;
        }
        __syncthreads();   // LDS reuse barrier before next ticket
    }
}

// ---------------------------------------------------------------------------
extern "C" void kernel_launch(void* const* d_in, const int* in_sizes, int n_in,
                              void* d_out, int out_size, void* d_ws, size_t ws_size,
                              hipStream_t stream) {
    const float* xyz = (const float*)d_in[0];
    float* out = (float*)d_out;

    // ws: [0..2048) sync region (ticket @0, done[b] @ (32+b*32)*4),
    //     then centers (B*NPOINT*3 floats)
    unsigned* syncb = (unsigned*)d_ws;
    float* centers = (float*)((char*)d_ws + 2048);

    static PermTab tab = build_tab();  // deterministic, host-only

    (void)hipMemsetAsync(syncb, 0, 2048, stream);
    fused_kernel<<<GRID_BLOCKS, NTHREADS, 0, stream>>>(xyz, centers, syncb, out, tab);
}